// Round 1
// 959.524 us; speedup vs baseline: 1.7078x; 1.7078x over previous
//
#include <hip/hip_runtime.h>
#include <math.h>

#define ACT_NONE 0
#define ACT_ELU  1
#define ACT_TANH 2

typedef unsigned short u16;
typedef unsigned int   u32;
typedef __attribute__((ext_vector_type(8))) short short8;  // 8 bf16 (4 VGPRs)
typedef __attribute__((ext_vector_type(4))) float f32x4;

__device__ __forceinline__ float eluf(float v) { return v > 0.f ? v : __expf(v) - 1.f; }
__device__ __forceinline__ float tanh_fast(float v) {
    // 1 - 2/(e^2v + 1): -> +1 for v->+inf (e^2v=inf), -> -1 for v->-inf. No NaN.
    float t = __expf(2.f * v);
    return 1.f - 2.f / (t + 1.f);
}
// fp32 -> bf16 round-nearest-even
__device__ __forceinline__ u16 bf16_rne(float x) {
    u32 u = __float_as_uint(x);
    u32 r = u + 0x7FFFu + ((u >> 16) & 1u);
    return (u16)(r >> 16);
}

// ---------------------------------------------------------------------------
// Transpose + fp32->bf16(hi/lo) convert.
// in: fp32 [K][N] row-major.  out: bf16 [Npad rows][ldo] (n-major, k-contiguous),
// zero-filled outside [K,N]. Grid: (ceil(Kpad/32), Npad/32), 256 threads.
// ---------------------------------------------------------------------------
__global__ __launch_bounds__(256) void convT(
    const float* __restrict__ in, int K, int N,
    u16* __restrict__ outHi, u16* __restrict__ outLo, int ldo)
{
    __shared__ float tile[32][33];
    const int t  = threadIdx.x;
    const int kt = blockIdx.x * 32;
    const int nt = blockIdx.y * 32;
    {
        int r = t >> 3, c = (t & 7) * 4;
        int gk = kt + r;
        float4 v = {0.f, 0.f, 0.f, 0.f};
        if (gk < K) {
            const float* p = in + (size_t)gk * N + nt + c;
            if (nt + c + 3 < N) {
                v = *reinterpret_cast<const float4*>(p);
            } else {
                if (nt + c + 0 < N) v.x = p[0];
                if (nt + c + 1 < N) v.y = p[1];
                if (nt + c + 2 < N) v.z = p[2];
                if (nt + c + 3 < N) v.w = p[3];
            }
        }
        tile[r][c] = v.x; tile[r][c + 1] = v.y; tile[r][c + 2] = v.z; tile[r][c + 3] = v.w;
    }
    __syncthreads();
    {
        int r = t >> 3, c = (t & 7) * 4;   // r = n within tile, c = k within tile
        ushort4 h, l;
        float f[4];
#pragma unroll
        for (int e = 0; e < 4; ++e) f[e] = tile[c + e][r];
        u16 hh[4], ll[4];
#pragma unroll
        for (int e = 0; e < 4; ++e) {
            hh[e] = bf16_rne(f[e]);
            float hf = __uint_as_float((u32)hh[e] << 16);
            ll[e] = bf16_rne(f[e] - hf);
        }
        h.x = hh[0]; h.y = hh[1]; h.z = hh[2]; h.w = hh[3];
        l.x = ll[0]; l.y = ll[1]; l.z = ll[2]; l.w = ll[3];
        size_t o = (size_t)(nt + r) * ldo + kt + c;
        *reinterpret_cast<ushort4*>(outHi + o) = h;
        *reinterpret_cast<ushort4*>(outLo + o) = l;
    }
}

// ---------------------------------------------------------------------------
// bf16x3 split-fp32 MFMA GEMM: C = act(A @ B + bias)   (or atomic += A@B)
//   A: fp32 [1024][lda], split to bf16 hi/lo in staging (3-term emulation:
//      Ahi*Bhi + Ahi*Blo + Alo*Bhi -> ~2^-17 relative error).
//   B: pre-transposed bf16 [Npad][ldb] hi + lo (n-major, k-contiguous).
// 128x128 tile, BK=32, 256 threads = 4 waves (2x2 of 64x64), 16x16x32 MFMA.
// M must be a multiple of 128 (here 1024). K-range [z*kChunk, z*kChunk+kChunk)
// must be a multiple of 32. Ncols guards atomic stores (padded B rows are 0).
// LDS rows padded to 40 u16 (80 B = 16B-aligned, bank-conflict-free frags).
// ---------------------------------------------------------------------------
template <int ACT, bool ATOMIC>
__global__ __launch_bounds__(256) void mgemm(
    const float* __restrict__ A, int lda,
    const u16* __restrict__ Bhi, const u16* __restrict__ Blo, int ldb,
    const float* __restrict__ bias,
    float* __restrict__ C, int ldc,
    int Ncols, int kChunk, int Ktot)
{
    __shared__ u16 As[2][128][40];   // [hi/lo][m][k]
    __shared__ u16 Bs[2][128][40];   // [hi/lo][n][k]

    const int tid  = threadIdx.x;
    const int m0   = blockIdx.y * 128;
    const int n0   = blockIdx.x * 128;
    const int kbeg = blockIdx.z * kChunk;
    const int kend = min(Ktot, kbeg + kChunk);

    const int w  = tid >> 6;
    const int wm = (w >> 1) * 64;
    const int wn = (w & 1) * 64;
    const int ln = tid & 63;
    const int fr = ln & 15;        // fragment row/col
    const int kh = ln >> 4;        // k-group (8 bf16 each)

    const int srow = tid >> 1;          // staging row 0..127
    const int skq  = (tid & 1) * 16;    // staging k-offset 0/16

    f32x4 acc[4][4];
#pragma unroll
    for (int i = 0; i < 4; ++i)
#pragma unroll
        for (int j = 0; j < 4; ++j) {
            f32x4 z = {0.f, 0.f, 0.f, 0.f};
            acc[i][j] = z;
        }

    for (int k0 = kbeg; k0 < kend; k0 += 32) {
        // ---- stage A: read fp32, split hi/lo bf16 ----
        {
            const float* p = A + (size_t)(m0 + srow) * lda + k0 + skq;
            alignas(16) float vv[16];
            *reinterpret_cast<float4*>(&vv[0])  = reinterpret_cast<const float4*>(p)[0];
            *reinterpret_cast<float4*>(&vv[4])  = reinterpret_cast<const float4*>(p)[1];
            *reinterpret_cast<float4*>(&vv[8])  = reinterpret_cast<const float4*>(p)[2];
            *reinterpret_cast<float4*>(&vv[12]) = reinterpret_cast<const float4*>(p)[3];
            alignas(16) u16 h[16], l[16];
#pragma unroll
            for (int e = 0; e < 16; ++e) {
                u16 hh = bf16_rne(vv[e]);
                h[e] = hh;
                float hf = __uint_as_float((u32)hh << 16);
                l[e] = bf16_rne(vv[e] - hf);
            }
            *reinterpret_cast<uint4*>(&As[0][srow][skq])     = *reinterpret_cast<uint4*>(&h[0]);
            *reinterpret_cast<uint4*>(&As[0][srow][skq + 8]) = *reinterpret_cast<uint4*>(&h[8]);
            *reinterpret_cast<uint4*>(&As[1][srow][skq])     = *reinterpret_cast<uint4*>(&l[0]);
            *reinterpret_cast<uint4*>(&As[1][srow][skq + 8]) = *reinterpret_cast<uint4*>(&l[8]);
        }
        // ---- stage B: pre-converted bf16 hi/lo, k-contiguous ----
        {
            const u16* p = Bhi + (size_t)(n0 + srow) * ldb + k0 + skq;
            uint4 u0 = reinterpret_cast<const uint4*>(p)[0];
            uint4 u1 = reinterpret_cast<const uint4*>(p)[1];
            *reinterpret_cast<uint4*>(&Bs[0][srow][skq])     = u0;
            *reinterpret_cast<uint4*>(&Bs[0][srow][skq + 8]) = u1;
            const u16* q = Blo + (size_t)(n0 + srow) * ldb + k0 + skq;
            uint4 v0 = reinterpret_cast<const uint4*>(q)[0];
            uint4 v1 = reinterpret_cast<const uint4*>(q)[1];
            *reinterpret_cast<uint4*>(&Bs[1][srow][skq])     = v0;
            *reinterpret_cast<uint4*>(&Bs[1][srow][skq + 8]) = v1;
        }
        __syncthreads();

        // ---- fragments + MFMA (A-row = lane&15, k = (lane>>4)*8 + e) ----
        short8 ah[4], al[4], bh[4], bl[4];
#pragma unroll
        for (int i = 0; i < 4; ++i) {
            ah[i] = *reinterpret_cast<const short8*>(&As[0][wm + i * 16 + fr][kh * 8]);
            al[i] = *reinterpret_cast<const short8*>(&As[1][wm + i * 16 + fr][kh * 8]);
        }
#pragma unroll
        for (int j = 0; j < 4; ++j) {
            bh[j] = *reinterpret_cast<const short8*>(&Bs[0][wn + j * 16 + fr][kh * 8]);
            bl[j] = *reinterpret_cast<const short8*>(&Bs[1][wn + j * 16 + fr][kh * 8]);
        }
#pragma unroll
        for (int i = 0; i < 4; ++i)
#pragma unroll
            for (int j = 0; j < 4; ++j) {
                acc[i][j] = __builtin_amdgcn_mfma_f32_16x16x32_bf16(ah[i], bh[j], acc[i][j], 0, 0, 0);
                acc[i][j] = __builtin_amdgcn_mfma_f32_16x16x32_bf16(ah[i], bl[j], acc[i][j], 0, 0, 0);
                acc[i][j] = __builtin_amdgcn_mfma_f32_16x16x32_bf16(al[i], bh[j], acc[i][j], 0, 0, 0);
            }
        __syncthreads();
    }

    // ---- epilogue: D mapping col = lane&15, row = (lane>>4)*4 + p  [m89] ----
#pragma unroll
    for (int j = 0; j < 4; ++j) {
        const int col = n0 + wn + j * 16 + fr;
        float bv = 0.f;
        if (!ATOMIC) bv = bias[col];
#pragma unroll
        for (int i = 0; i < 4; ++i) {
            const int rowb = m0 + wm + i * 16 + kh * 4;
#pragma unroll
            for (int p = 0; p < 4; ++p) {
                float v = acc[i][j][p];
                const int row = rowb + p;
                if (ATOMIC) {
                    if (col < Ncols) atomicAdd(&C[(size_t)row * ldc + col], v);
                } else {
                    v += bv;
                    if (ACT == ACT_TANH) v = tanh_fast(v);
                    else if (ACT == ACT_ELU) v = eluf(v);
                    C[(size_t)row * ldc + col] = v;
                }
            }
        }
    }
}

// ---------------------------------------------------------------------------
__global__ __launch_bounds__(256) void zero_f32(float* __restrict__ p, int n)
{
    int i = blockIdx.x * 256 + threadIdx.x;
    if (i < n) p[i] = 0.f;
}

__global__ __launch_bounds__(256) void bias_elu_inplace(
    float* __restrict__ p, const float* __restrict__ bias, int n, int N)
{
    int i = blockIdx.x * 256 + threadIdx.x;
    if (i < n) p[i] = eluf(p[i] + bias[i % N]);
}

// ---------------------------------------------------------------------------
// Row-per-block GEMM for small N/K: out[m,:] = act(A[m,:] @ W + bias)
// ---------------------------------------------------------------------------
template <int ACT>
__global__ __launch_bounds__(256) void rowgemm(
    const float* __restrict__ A, int strideA,
    const float* __restrict__ W, const float* __restrict__ bias,
    float* __restrict__ out, int strideOut, int padWidth,
    int N, int K)
{
    __shared__ float Arow[928];
    const int m = blockIdx.x;
    const int t = threadIdx.x;
    for (int k = t; k < K; k += 256) Arow[k] = A[(size_t)m * strideA + k];
    __syncthreads();
    for (int n = t; n < padWidth; n += 256) {
        float s = 0.f;
        if (n < N) {
            s = bias[n];
            for (int k = 0; k < K; ++k) s = fmaf(Arow[k], W[(size_t)k * N + n], s);
            if (ACT == ACT_ELU) s = eluf(s);
        }
        out[(size_t)m * strideOut + n] = s;
    }
}

// ---------------------------------------------------------------------------
// Latent: Bmat = W .* relu(j-i); eps = exp(logvar/2)*noise;
// z = forward substitution of z(I-B)=eps; Bz = z@Bmat.
// ---------------------------------------------------------------------------
__global__ __launch_bounds__(256) void latent_kernel(
    const float* __restrict__ logvar,
    const float* __restrict__ eps_noise,
    const float* __restrict__ Wlat,
    float* __restrict__ z_ws,
    float* __restrict__ out)
{
    __shared__ float Bm[256];
    const int t = threadIdx.x;
    {
        int i = t >> 4, j = t & 15;
        float v = (j > i) ? Wlat[t] * (float)(j - i) : 0.f;
        Bm[t] = v;
        if (blockIdx.x == 0) out[49152 + t] = v;        // Bmat
    }
    __syncthreads();

    const int b = blockIdx.x * 256 + t;
    float lv[16], z[16];
#pragma unroll
    for (int j = 0; j < 16; ++j) lv[j] = logvar[b * 16 + j];
#pragma unroll
    for (int j = 0; j < 16; ++j) {
        float s = __expf(0.5f * fminf(lv[j], 80.f)) * eps_noise[b * 16 + j];
        for (int i = 0; i < j; ++i) s = fmaf(z[i], Bm[i * 16 + j], s);
        z[j] = s;
    }
#pragma unroll
    for (int j = 0; j < 16; ++j) {
        float bz = 0.f;
#pragma unroll
        for (int i = 0; i < 16; ++i) bz = fmaf(z[i], Bm[i * 16 + j], bz);
        out[b * 16 + j]         = z[j];
        out[16384 + b * 16 + j] = lv[j];
        out[32768 + b * 16 + j] = bz;
        z_ws[b * 16 + j] = z[j];
    }
}

// ---------------------------------------------------------------------------
// Workspace layout (bytes) — total 156,221,440 (~149 MB):
//   h1     fp32 [1024][900]      @ 0
//   h2     fp32 [1024][300]      @ 3,686,400
//   lv     fp32 [1024][16]       @ 4,915,200
//   zf     fp32 [1024][16]       @ 4,980,736
//   g1     fp32 [1024][300]      @ 5,046,272
//   g2     fp32 [1024][320]      @ 6,275,072   (cols 300..319 = 0)
//   w1t_hi bf16 [1024][27648]    @ 7,585,792   (rows 900..1023 = 0)
//   w1t_lo bf16 [1024][27648]    @ 64,208,896
//   w3t_hi bf16 [27648][320]     @ 120,832,000 (cols 300..319 = 0)
//   w3t_lo bf16 [27648][320]     @ 138,526,720
// Output (fp32 flat): z[16384] | logvar[16384] | Bz[16384] | Bmat[256] | xhat
// ---------------------------------------------------------------------------
extern "C" void kernel_launch(void* const* d_in, const int* in_sizes, int n_in,
                              void* d_out, int out_size, void* d_ws, size_t ws_size,
                              hipStream_t stream)
{
    const float* x       = (const float*)d_in[0];   // [1024, 27648]
    const float* eps_n   = (const float*)d_in[1];   // [1024, 16]
    const float* enc_w1  = (const float*)d_in[2];   // [27648, 900]
    const float* enc_b1  = (const float*)d_in[3];
    const float* enc_w2  = (const float*)d_in[4];   // [900, 300]
    const float* enc_b2  = (const float*)d_in[5];
    const float* lv_w    = (const float*)d_in[6];   // [300, 16]
    const float* lv_b    = (const float*)d_in[7];
    const float* Wlat    = (const float*)d_in[8];   // [16, 16]
    const float* dec_w1  = (const float*)d_in[9];   // [16, 300]
    const float* dec_b1  = (const float*)d_in[10];
    const float* dec_w2  = (const float*)d_in[11];  // [300, 300]
    const float* dec_b2  = (const float*)d_in[12];
    const float* dec_w3  = (const float*)d_in[13];  // [300, 27648]
    const float* dec_b3  = (const float*)d_in[14];

    char* ws = (char*)d_ws;
    float* h1     = (float*)(ws + 0);
    float* h2     = (float*)(ws + 3686400);
    float* lv     = (float*)(ws + 4915200);
    float* zf     = (float*)(ws + 4980736);
    float* g1     = (float*)(ws + 5046272);
    float* g2     = (float*)(ws + 6275072);
    u16*   w1t_hi = (u16*)(ws + 7585792);
    u16*   w1t_lo = (u16*)(ws + 64208896);
    u16*   w3t_hi = (u16*)(ws + 120832000);
    u16*   w3t_lo = (u16*)(ws + 138526720);

    float* out = (float*)d_out;

    // 0) weight transpose + bf16 hi/lo split
    //    enc_w1 [27648][900] -> w1t [1024][27648]
    convT<<<dim3(864, 32), 256, 0, stream>>>(enc_w1, 27648, 900, w1t_hi, w1t_lo, 27648);
    //    dec_w3 [300][27648] -> w3t [27648][320]
    convT<<<dim3(10, 864), 256, 0, stream>>>(dec_w3, 300, 27648, w3t_hi, w3t_lo, 320);

    // 1) zero split-K accumulator
    zero_f32<<<3600, 256, 0, stream>>>(h1, 921600);

    // 2) h1 += x @ enc_w1   (bf16x3 MFMA, split-K=8, fp32 atomics)
    mgemm<ACT_NONE, true><<<dim3(8, 8, 8), 256, 0, stream>>>(
        x, 27648, w1t_hi, w1t_lo, 27648, nullptr,
        h1, 900, 900, 3456, 27648);

    // 3) h1 = elu(h1 + enc_b1)
    bias_elu_inplace<<<3600, 256, 0, stream>>>(h1, enc_b1, 921600, 900);

    // 4) h2 = elu(h1 @ enc_w2 + enc_b2)
    rowgemm<ACT_ELU><<<1024, 256, 0, stream>>>(
        h1, 900, enc_w2, enc_b2, h2, 300, 300, 300, 900);

    // 5) logvar = h2 @ lv_w + lv_b
    rowgemm<ACT_NONE><<<1024, 256, 0, stream>>>(
        h2, 300, lv_w, lv_b, lv, 16, 16, 16, 300);

    // 6) latent: z / logvar / Bz / Bmat outputs + fp32 z scratch
    latent_kernel<<<4, 256, 0, stream>>>(lv, eps_n, Wlat, zf, out);

    // 7) g1 = elu(z @ dec_w1 + dec_b1)
    rowgemm<ACT_ELU><<<1024, 256, 0, stream>>>(
        zf, 16, dec_w1, dec_b1, g1, 300, 300, 300, 16);

    // 8) g2 = elu(g1 @ dec_w2 + dec_b2), stride 320, cols 300..319 zeroed
    rowgemm<ACT_ELU><<<1024, 256, 0, stream>>>(
        g1, 300, dec_w2, dec_b2, g2, 320, 320, 300, 300);

    // 9) xhat = tanh(g2 @ dec_w3 + dec_b3)   (bf16x3 MFMA, K=320 incl. pad)
    mgemm<ACT_TANH, false><<<dim3(216, 8, 1), 256, 0, stream>>>(
        g2, 320, w3t_hi, w3t_lo, 320, dec_b3,
        out + 49408, 27648, 27648, 320, 320);
}